// Round 7
// baseline (243.446 us; speedup 1.0000x reference)
//
#include <hip/hip_runtime.h>
#include <hip/hip_bf16.h>

// GCN 2-layer + mean-pool + log_softmax on gfx950.
// R7: csr entry = src(16b)|fp16(dis[src])(16b) -> gemm1 independent of graph
//     prep; count+gemm1 overlapped in one phase1 launch. gemm2 fused into
//     agg1 (h1 never hits memory). 8 launches.

#define NN 50000
#define EE 600000
#define FIN 128
#define HH 128
#define CC 16
#define GG 500
#define ETOT (EE + NN)   // 650000
#define SBLK 196         // ceil(NN/256) scan blocks
#define GB 782           // gemm1 tiles = ceil(NN/64)
#define PB 3126          // phase1 blocks: 782 gemm1 (bid%4==0) + 2344 count

typedef unsigned short ushort_t;
typedef unsigned int uint_t;

typedef __attribute__((ext_vector_type(8))) short bf16x8;
typedef __attribute__((ext_vector_type(4))) ushort_t u16x4;
typedef __attribute__((ext_vector_type(4))) float f32x4;
typedef __attribute__((ext_vector_type(2))) float f32x2;

__device__ inline ushort_t f2bf(float f) {
    uint_t u = __float_as_uint(f);
    u = (u + 0x7FFFu + ((u >> 16) & 1u)) >> 16;   // RNE
    return (ushort_t)u;
}
__device__ inline float bf2f(ushort_t b) {
    return __uint_as_float(((uint_t)b) << 16);
}
__device__ inline ushort_t f2h(float f) {
    _Float16 h = (_Float16)f; ushort_t u; __builtin_memcpy(&u, &h, 2); return u;
}
__device__ inline float h2f(ushort_t u) {
    _Float16 h; __builtin_memcpy(&h, &u, 2); return (float)h;
}

// ---------------- init ----------------
__global__ void init_kernel(int* cnt, float* pooled) {
    int i = blockIdx.x * blockDim.x + threadIdx.x;
    if (i < NN) cnt[i] = 0;
    if (i < GG * CC) pooled[i] = 0.0f;
}

// ---------------- phase1: count (atomics) + gemm1 (MFMA) overlapped ----------
// bid%4==0 -> gemm1 tile bid>>2 (782 tiles); else count block.
__global__ __launch_bounds__(256) void phase1_kernel(const int* __restrict__ edge_dst,
                                                     int* __restrict__ cnt,
                                                     int* __restrict__ seq,
                                                     const float* __restrict__ x,
                                                     const float* __restrict__ W1,
                                                     unsigned char* __restrict__ hb8) {
    __shared__ ushort_t xs[64 * 136];
    __shared__ ushort_t wt[128 * 136];
    int bid = blockIdx.x;
    int t = threadIdx.x;
    if ((bid & 3) == 0) {
        // ---- gemm1: hb8 = fp8(x @ W1), unscaled ----
        int row0 = (bid >> 2) * 64;
        for (int i = 0; i < 8; i++) {
            int slot = t + i * 256;
            int r = slot >> 5, k4 = slot & 31;
            int gr = row0 + r;
            float4 v = (gr < NN) ? ((const float4*)x)[gr * 32 + k4]
                                 : make_float4(0.f, 0.f, 0.f, 0.f);
            u16x4 bv = { f2bf(v.x), f2bf(v.y), f2bf(v.z), f2bf(v.w) };
            *(u16x4*)(&xs[r * 136 + k4 * 4]) = bv;
        }
        for (int i = 0; i < 16; i++) {
            int slot = t + i * 256;
            int k = slot >> 5, c4 = slot & 31;
            float4 v = ((const float4*)W1)[k * 32 + c4];
            wt[(c4 * 4 + 0) * 136 + k] = f2bf(v.x);
            wt[(c4 * 4 + 1) * 136 + k] = f2bf(v.y);
            wt[(c4 * 4 + 2) * 136 + k] = f2bf(v.z);
            wt[(c4 * 4 + 3) * 136 + k] = f2bf(v.w);
        }
        __syncthreads();

        int wave = t >> 6, lane = t & 63;
        int m = lane & 15, quad = lane >> 4;
        f32x4 acc[8];
        for (int ct = 0; ct < 8; ct++) acc[ct] = (f32x4)(0.0f);
        for (int ko = 0; ko < 4; ko++) {
            bf16x8 a = *(const bf16x8*)(&xs[(16 * wave + m) * 136 + ko * 32 + quad * 8]);
            for (int ct = 0; ct < 8; ct++) {
                bf16x8 b = *(const bf16x8*)(&wt[(ct * 16 + m) * 136 + ko * 32 + quad * 8]);
                acc[ct] = __builtin_amdgcn_mfma_f32_16x16x32_bf16(a, b, acc[ct], 0, 0, 0);
            }
        }
        // D: col = lane&15, row = quad*4 + reg
        for (int ct = 0; ct < 8; ct++) {
            int gcol = ct * 16 + m;
            for (int r = 0; r < 4; r++) {
                int grow = row0 + wave * 16 + quad * 4 + r;
                if (grow < NN) {
                    int p = __builtin_amdgcn_cvt_pk_fp8_f32(acc[ct][r], 0.0f, 0, false);
                    hb8[(size_t)grow * HH + gcol] = (unsigned char)(p & 0xFF);
                }
            }
        }
    } else {
        // ---- count: the single scattered-atomic pass ----
        int cidx = bid - (bid >> 2) - 1;
        int idx = cidx * 256 + t;
        if (idx < EE) seq[idx] = atomicAdd(&cnt[edge_dst[idx]], 1);
    }
}

// ---------------- block-scan helper ----------------
__device__ inline int block_excl_scan(int v, int t, int* total) {
    __shared__ int wsum[4];
    int lane = t & 63, wv = t >> 6;
    int inc = v;
    for (int off = 1; off < 64; off <<= 1) {
        int n = __shfl_up(inc, off);
        if (lane >= off) inc += n;
    }
    if (lane == 63) wsum[wv] = inc;
    __syncthreads();
    int off_w = 0;
    for (int w = 0; w < wv; w++) off_w += wsum[w];
    *total = wsum[0] + wsum[1] + wsum[2] + wsum[3];
    return off_w + inc - v;
}

// ---------------- scan A ----------------
__global__ __launch_bounds__(256) void scanA_kernel(const int* __restrict__ cnt,
                                                    int* __restrict__ rowptr,
                                                    float* __restrict__ dis,
                                                    int* __restrict__ bsum) {
    int t = threadIdx.x;
    int i = blockIdx.x * 256 + t;
    int d = 0;
    if (i < NN) {
        d = cnt[i] + 1;                        // +1 self-loop
        dis[i] = rsqrtf((float)d);
    }
    int total;
    int excl = block_excl_scan(d, t, &total);
    if (i < NN) rowptr[i] = excl;
    if (t == 0) bsum[blockIdx.x] = total;
}

// ---------------- scan BC ----------------
__global__ __launch_bounds__(256) void scanBC_kernel(int* __restrict__ rowptr,
                                                     const int* __restrict__ bsum) {
    __shared__ int sb[256];
    int t = threadIdx.x;
    int v = (t < SBLK) ? bsum[t] : 0;
    int total;
    int ex = block_excl_scan(v, t, &total);
    sb[t] = ex;
    __syncthreads();
    int myoff = sb[blockIdx.x];
    int i = blockIdx.x * 256 + t;
    if (i < NN) rowptr[i] += myoff;
    if (blockIdx.x == 0 && t == 0) rowptr[NN] = ETOT;
}

// ---------------- CSR fill: entry = src | fp16(dis[src])<<16 ----------------
__global__ void fill_kernel(const int* __restrict__ edge_src,
                            const int* __restrict__ edge_dst,
                            const float* __restrict__ dis,
                            const int* __restrict__ rowptr,
                            const int* __restrict__ seq,
                            uint_t* __restrict__ csr) {
    int idx = blockIdx.x * blockDim.x + threadIdx.x;
    if (idx < EE) {
        int s = edge_src[idx], d = edge_dst[idx];
        csr[rowptr[d] + seq[idx]] = (uint_t)s | ((uint_t)f2h(dis[s]) << 16);
    } else if (idx < ETOT) {
        int n = idx - EE;
        csr[rowptr[n + 1] - 1] = (uint_t)n | ((uint_t)f2h(dis[n]) << 16);
    }
}

// ---------------- agg1 + gemm2 fused ----------------
// 16 nodes/block (4 waves x 4 nodes). Per node: wave gathers fp8 rows
// (8 edge slots x 8 feature-lanes), slot-reduce -> full h1 row per lane,
// relu(dis[d]*sum + b1), then in-wave h1 @ W2 (slot s -> channels 2s,2s+1,
// reduce over sub) -> h2b row (bf16, unscaled).
__global__ __launch_bounds__(256) void agg1_kernel(const unsigned char* __restrict__ hb8,
                                                   const int* __restrict__ rowptr,
                                                   const uint_t* __restrict__ csr,
                                                   const float* __restrict__ dis,
                                                   const float* __restrict__ b1,
                                                   const float* __restrict__ W2,
                                                   ushort_t* __restrict__ h2b) {
    __shared__ float w2s[HH * CC];
    __shared__ float b1s[HH];
    int t = threadIdx.x;
    for (int i = t; i < HH * CC; i += 256) w2s[i] = W2[i];
    if (t < HH) b1s[t] = b1[t];
    __syncthreads();
    int wave = t >> 6, lane = t & 63;
    int slot = lane >> 3, sub = lane & 7;
    for (int it = 0; it < 4; it++) {
        int node = blockIdx.x * 16 + wave * 4 + it;
        int e0 = rowptr[node], e1 = rowptr[node + 1];
        float acc[16];
        for (int j = 0; j < 16; j++) acc[j] = 0.0f;
        for (int e = e0 + slot; e < e1; e += 8) {
            uint_t ent = csr[e];
            float w = h2f((ushort_t)(ent >> 16));
            uint4 hv = *(const uint4*)(hb8 + (size_t)(ent & 0xFFFFu) * HH + sub * 16);
            uint_t words[4] = { hv.x, hv.y, hv.z, hv.w };
            for (int q = 0; q < 4; q++) {
                f32x2 lo = __builtin_amdgcn_cvt_pk_f32_fp8(words[q], false);
                f32x2 hi = __builtin_amdgcn_cvt_pk_f32_fp8(words[q], true);
                acc[q * 4 + 0] += w * lo[0];
                acc[q * 4 + 1] += w * lo[1];
                acc[q * 4 + 2] += w * hi[0];
                acc[q * 4 + 3] += w * hi[1];
            }
        }
        for (int j = 0; j < 16; j++) {
            acc[j] += __shfl_xor(acc[j], 8);
            acc[j] += __shfl_xor(acc[j], 16);
            acc[j] += __shfl_xor(acc[j], 32);
        }
        // h1 row fragment (features sub*16 .. sub*16+15), replicated per slot
        float dn = dis[node];
        float h1v[16];
        for (int j = 0; j < 16; j++)
            h1v[j] = fmaxf(dn * acc[j] + b1s[sub * 16 + j], 0.0f);
        // gemm2: slot s computes channels 2s, 2s+1
        float p0 = 0.0f, p1 = 0.0f;
        for (int j = 0; j < 16; j++) {
            float hv = h1v[j];
            p0 += hv * w2s[(sub * 16 + j) * CC + 2 * slot];
            p1 += hv * w2s[(sub * 16 + j) * CC + 2 * slot + 1];
        }
        p0 += __shfl_xor(p0, 1); p0 += __shfl_xor(p0, 2); p0 += __shfl_xor(p0, 4);
        p1 += __shfl_xor(p1, 1); p1 += __shfl_xor(p1, 2); p1 += __shfl_xor(p1, 4);
        if (sub == 0) {
            uint_t packed = (uint_t)f2bf(p0) | ((uint_t)f2bf(p1) << 16);
            *(uint_t*)(h2b + (size_t)node * CC + 2 * slot) = packed;
        }
    }
}

// ---------------- agg2 + pool fused, sorted-batch segmented flush ----------------
__global__ __launch_bounds__(256) void agg2pool_kernel(const ushort_t* __restrict__ h2b,
                                                       const int* __restrict__ rowptr,
                                                       const uint_t* __restrict__ csr,
                                                       const float* __restrict__ dis,
                                                       const float* __restrict__ b2,
                                                       const int* __restrict__ batch,
                                                       float* __restrict__ pooled) {
    __shared__ float vals[16][16];
    __shared__ int gid[16];
    int t = threadIdx.x;
    int local = t >> 4, c = t & 15;
    int node = blockIdx.x * 16 + local;
    int e0 = rowptr[node], e1 = rowptr[node + 1];
    float acc = 0.0f;
    for (int e = e0; e < e1; e++) {
        uint_t ent = csr[e];
        acc += h2f((ushort_t)(ent >> 16)) * bf2f(h2b[(size_t)(ent & 0xFFFFu) * CC + c]);
    }
    vals[local][c] = acc * dis[node] + b2[c];
    if (c == 0) gid[local] = batch[node];
    __syncthreads();
    if (t < 16) {                      // walker for channel t
        float run = 0.0f;
        for (int i = 0; i < 16; i++) {
            run += vals[i][t];
            if (i == 15 || gid[i + 1] != gid[i]) {
                atomicAdd(&pooled[gid[i] * CC + t], run);
                run = 0.0f;
            }
        }
    }
}

// ---------------- mean + log_softmax (counts via binary search) ----------------
__global__ void lsm_kernel(const float* __restrict__ pooled,
                           const int* __restrict__ batch,
                           float* __restrict__ out) {
    int idx = blockIdx.x * blockDim.x + threadIdx.x;
    int g = idx >> 4, c = idx & 15;
    if (g >= GG) return;
    int lo = 0, hi = NN;
    while (lo < hi) { int mid = (lo + hi) >> 1; if (batch[mid] < g) lo = mid + 1; else hi = mid; }
    int lo2 = lo, hi2 = NN;
    while (lo2 < hi2) { int mid = (lo2 + hi2) >> 1; if (batch[mid] < g + 1) lo2 = mid + 1; else hi2 = mid; }
    float cnt = (float)(lo2 - lo);
    float v = pooled[g * CC + c] / fmaxf(cnt, 1.0f);
    float m = v;
    for (int off = 8; off >= 1; off >>= 1) m = fmaxf(m, __shfl_xor(m, off, 16));
    float s = expf(v - m);
    for (int off = 8; off >= 1; off >>= 1) s += __shfl_xor(s, off, 16);
    out[g * CC + c] = v - m - logf(s);
}

extern "C" void kernel_launch(void* const* d_in, const int* in_sizes, int n_in,
                              void* d_out, int out_size, void* d_ws, size_t ws_size,
                              hipStream_t stream) {
    const float* x  = (const float*)d_in[0];
    const float* W1 = (const float*)d_in[1];
    const float* b1 = (const float*)d_in[2];
    const float* W2 = (const float*)d_in[3];
    const float* b2 = (const float*)d_in[4];
    const int* edge_src = (const int*)d_in[5];
    const int* edge_dst = (const int*)d_in[6];
    const int* batch    = (const int*)d_in[7];
    float* out = (float*)d_out;

    char* ws = (char*)d_ws;
    size_t off = 0;
    auto alloc = [&](size_t bytes) {
        void* p = ws + off;
        off += (bytes + 255) & ~size_t(255);
        return p;
    };
    int*   cnt     = (int*)  alloc(NN * 4);
    float* dis     = (float*)alloc(NN * 4);
    int*   rowptr  = (int*)  alloc((NN + 1) * 4);
    int*   seq     = (int*)  alloc(EE * 4);
    int*   bsum    = (int*)  alloc(SBLK * 4);
    uint_t* csr    = (uint_t*)alloc((size_t)ETOT * 4);
    unsigned char* hb8 = (unsigned char*)alloc((size_t)NN * HH);
    ushort_t* h2b  = (ushort_t*)alloc((size_t)NN * CC * 2);
    float* pooled  = (float*)alloc(GG * CC * 4);

    const int B = 256;
    init_kernel<<<(NN + B - 1) / B, B, 0, stream>>>(cnt, pooled);
    phase1_kernel<<<PB, B, 0, stream>>>(edge_dst, cnt, seq, x, W1, hb8);
    scanA_kernel<<<SBLK, B, 0, stream>>>(cnt, rowptr, dis, bsum);
    scanBC_kernel<<<SBLK, B, 0, stream>>>(rowptr, bsum);
    fill_kernel<<<(ETOT + B - 1) / B, B, 0, stream>>>(edge_src, edge_dst, dis,
                                                      rowptr, seq, csr);
    agg1_kernel<<<NN / 16, B, 0, stream>>>(hb8, rowptr, csr, dis, b1, W2, h2b);
    agg2pool_kernel<<<NN / 16, B, 0, stream>>>(h2b, rowptr, csr, dis, b2, batch, pooled);
    lsm_kernel<<<(GG * CC + B - 1) / B, B, 0, stream>>>(pooled, batch, out);
}

// Round 8
// 219.433 us; speedup vs baseline: 1.1094x; 1.1094x over previous
//
#include <hip/hip_runtime.h>
#include <hip/hip_bf16.h>

// GCN 2-layer + mean-pool + log_softmax on gfx950.
// R8: unfused count (R7's phase1 fusion starved the atomic pass: 51KB LDS
//     reserved by count blocks -> 14% occupancy). Kept: packed src|fp16(w)
//     CSR, agg1+gemm2 fusion. gemm1 wt staging re-mapped (c,k4)+stride-140
//     to kill the 6.4M LDS bank conflicts.

#define NN 50000
#define EE 600000
#define FIN 128
#define HH 128
#define CC 16
#define GG 500
#define ETOT (EE + NN)   // 650000
#define SBLK 196         // ceil(NN/256) scan blocks
#define WTS 140          // wt row stride (elements): 70-word lane stride, gcd(6,32)=2

typedef unsigned short ushort_t;
typedef unsigned int uint_t;

typedef __attribute__((ext_vector_type(8))) short bf16x8;
typedef __attribute__((ext_vector_type(4))) ushort_t u16x4;
typedef __attribute__((ext_vector_type(4))) float f32x4;
typedef __attribute__((ext_vector_type(2))) float f32x2;

__device__ inline ushort_t f2bf(float f) {
    uint_t u = __float_as_uint(f);
    u = (u + 0x7FFFu + ((u >> 16) & 1u)) >> 16;   // RNE
    return (ushort_t)u;
}
__device__ inline float bf2f(ushort_t b) {
    return __uint_as_float(((uint_t)b) << 16);
}
__device__ inline ushort_t f2h(float f) {
    _Float16 h = (_Float16)f; ushort_t u; __builtin_memcpy(&u, &h, 2); return u;
}
__device__ inline float h2f(ushort_t u) {
    _Float16 h; __builtin_memcpy(&h, &u, 2); return (float)h;
}

// ---------------- init ----------------
__global__ void init_kernel(int* cnt, float* pooled) {
    int i = blockIdx.x * blockDim.x + threadIdx.x;
    if (i < NN) cnt[i] = 0;
    if (i < GG * CC) pooled[i] = 0.0f;
}

// ---------------- count: single scattered-atomic pass (no LDS, max occupancy) ----
__global__ void count_kernel(const int* __restrict__ edge_dst,
                             int* __restrict__ cnt, int* __restrict__ seq) {
    int idx = blockIdx.x * blockDim.x + threadIdx.x;
    if (idx < EE) seq[idx] = atomicAdd(&cnt[edge_dst[idx]], 1);
}

// ---------------- GEMM1: hb8 = fp8(x @ W1), unscaled ----------------
__global__ __launch_bounds__(256) void gemm1_kernel(const float* __restrict__ x,
                                                    const float* __restrict__ W1,
                                                    unsigned char* __restrict__ hb8) {
    __shared__ ushort_t xs[64 * 136];
    __shared__ ushort_t wt[128 * WTS];
    int t = threadIdx.x;
    int row0 = blockIdx.x * 64;
    // stage x tile: (r, k4) mapping, conflict-free
    for (int i = 0; i < 8; i++) {
        int slot = t + i * 256;
        int r = slot >> 5, k4 = slot & 31;
        int gr = row0 + r;
        float4 v = (gr < NN) ? ((const float4*)x)[gr * 32 + k4]
                             : make_float4(0.f, 0.f, 0.f, 0.f);
        u16x4 bv = { f2bf(v.x), f2bf(v.y), f2bf(v.z), f2bf(v.w) };
        *(u16x4*)(&xs[r * 136 + k4 * 4]) = bv;
    }
    // stage W1^T: (c, k4) mapping — 4 coalesced strided loads, one 8B store
    for (int i = 0; i < 16; i++) {
        int idx = t + i * 256;
        int c = idx & 127, k4 = idx >> 7;      // k4 in 0..31
        u16x4 bv = { f2bf(W1[(4 * k4 + 0) * HH + c]),
                     f2bf(W1[(4 * k4 + 1) * HH + c]),
                     f2bf(W1[(4 * k4 + 2) * HH + c]),
                     f2bf(W1[(4 * k4 + 3) * HH + c]) };
        *(u16x4*)(&wt[c * WTS + k4 * 4]) = bv;
    }
    __syncthreads();

    int wave = t >> 6, lane = t & 63;
    int m = lane & 15, quad = lane >> 4;
    f32x4 acc[8];
    for (int ct = 0; ct < 8; ct++) acc[ct] = (f32x4)(0.0f);
    for (int ko = 0; ko < 4; ko++) {
        bf16x8 a = *(const bf16x8*)(&xs[(16 * wave + m) * 136 + ko * 32 + quad * 8]);
        for (int ct = 0; ct < 8; ct++) {
            bf16x8 b = *(const bf16x8*)(&wt[(ct * 16 + m) * WTS + ko * 32 + quad * 8]);
            acc[ct] = __builtin_amdgcn_mfma_f32_16x16x32_bf16(a, b, acc[ct], 0, 0, 0);
        }
    }
    // D: col = lane&15, row = quad*4 + reg
    for (int ct = 0; ct < 8; ct++) {
        int gcol = ct * 16 + m;
        for (int r = 0; r < 4; r++) {
            int grow = row0 + wave * 16 + quad * 4 + r;
            if (grow < NN) {
                int p = __builtin_amdgcn_cvt_pk_fp8_f32(acc[ct][r], 0.0f, 0, false);
                hb8[(size_t)grow * HH + gcol] = (unsigned char)(p & 0xFF);
            }
        }
    }
}

// ---------------- block-scan helper ----------------
__device__ inline int block_excl_scan(int v, int t, int* total) {
    __shared__ int wsum[4];
    int lane = t & 63, wv = t >> 6;
    int inc = v;
    for (int off = 1; off < 64; off <<= 1) {
        int n = __shfl_up(inc, off);
        if (lane >= off) inc += n;
    }
    if (lane == 63) wsum[wv] = inc;
    __syncthreads();
    int off_w = 0;
    for (int w = 0; w < wv; w++) off_w += wsum[w];
    *total = wsum[0] + wsum[1] + wsum[2] + wsum[3];
    return off_w + inc - v;
}

// ---------------- scan A ----------------
__global__ __launch_bounds__(256) void scanA_kernel(const int* __restrict__ cnt,
                                                    int* __restrict__ rowptr,
                                                    float* __restrict__ dis,
                                                    int* __restrict__ bsum) {
    int t = threadIdx.x;
    int i = blockIdx.x * 256 + t;
    int d = 0;
    if (i < NN) {
        d = cnt[i] + 1;                        // +1 self-loop
        dis[i] = rsqrtf((float)d);
    }
    int total;
    int excl = block_excl_scan(d, t, &total);
    if (i < NN) rowptr[i] = excl;
    if (t == 0) bsum[blockIdx.x] = total;
}

// ---------------- scan BC ----------------
__global__ __launch_bounds__(256) void scanBC_kernel(int* __restrict__ rowptr,
                                                     const int* __restrict__ bsum) {
    __shared__ int sb[256];
    int t = threadIdx.x;
    int v = (t < SBLK) ? bsum[t] : 0;
    int total;
    int ex = block_excl_scan(v, t, &total);
    sb[t] = ex;
    __syncthreads();
    int myoff = sb[blockIdx.x];
    int i = blockIdx.x * 256 + t;
    if (i < NN) rowptr[i] += myoff;
    if (blockIdx.x == 0 && t == 0) rowptr[NN] = ETOT;
}

// ---------------- CSR fill: entry = src | fp16(dis[src])<<16 ----------------
__global__ void fill_kernel(const int* __restrict__ edge_src,
                            const int* __restrict__ edge_dst,
                            const float* __restrict__ dis,
                            const int* __restrict__ rowptr,
                            const int* __restrict__ seq,
                            uint_t* __restrict__ csr) {
    int idx = blockIdx.x * blockDim.x + threadIdx.x;
    if (idx < EE) {
        int s = edge_src[idx], d = edge_dst[idx];
        csr[rowptr[d] + seq[idx]] = (uint_t)s | ((uint_t)f2h(dis[s]) << 16);
    } else if (idx < ETOT) {
        int n = idx - EE;
        csr[rowptr[n + 1] - 1] = (uint_t)n | ((uint_t)f2h(dis[n]) << 16);
    }
}

// ---------------- agg1 + gemm2 fused ----------------
__global__ __launch_bounds__(256) void agg1_kernel(const unsigned char* __restrict__ hb8,
                                                   const int* __restrict__ rowptr,
                                                   const uint_t* __restrict__ csr,
                                                   const float* __restrict__ dis,
                                                   const float* __restrict__ b1,
                                                   const float* __restrict__ W2,
                                                   ushort_t* __restrict__ h2b) {
    __shared__ float w2s[HH * CC];
    __shared__ float b1s[HH];
    int t = threadIdx.x;
    for (int i = t; i < HH * CC; i += 256) w2s[i] = W2[i];
    if (t < HH) b1s[t] = b1[t];
    __syncthreads();
    int wave = t >> 6, lane = t & 63;
    int slot = lane >> 3, sub = lane & 7;
    for (int it = 0; it < 4; it++) {
        int node = blockIdx.x * 16 + wave * 4 + it;
        int e0 = rowptr[node], e1 = rowptr[node + 1];
        float acc[16];
        for (int j = 0; j < 16; j++) acc[j] = 0.0f;
        for (int e = e0 + slot; e < e1; e += 8) {
            uint_t ent = csr[e];
            float w = h2f((ushort_t)(ent >> 16));
            uint4 hv = *(const uint4*)(hb8 + (size_t)(ent & 0xFFFFu) * HH + sub * 16);
            uint_t words[4] = { hv.x, hv.y, hv.z, hv.w };
            for (int q = 0; q < 4; q++) {
                f32x2 lo = __builtin_amdgcn_cvt_pk_f32_fp8(words[q], false);
                f32x2 hi = __builtin_amdgcn_cvt_pk_f32_fp8(words[q], true);
                acc[q * 4 + 0] += w * lo[0];
                acc[q * 4 + 1] += w * lo[1];
                acc[q * 4 + 2] += w * hi[0];
                acc[q * 4 + 3] += w * hi[1];
            }
        }
        for (int j = 0; j < 16; j++) {
            acc[j] += __shfl_xor(acc[j], 8);
            acc[j] += __shfl_xor(acc[j], 16);
            acc[j] += __shfl_xor(acc[j], 32);
        }
        float dn = dis[node];
        float h1v[16];
        for (int j = 0; j < 16; j++)
            h1v[j] = fmaxf(dn * acc[j] + b1s[sub * 16 + j], 0.0f);
        // gemm2: slot s computes channels 2s, 2s+1
        float p0 = 0.0f, p1 = 0.0f;
        for (int j = 0; j < 16; j++) {
            float hv = h1v[j];
            p0 += hv * w2s[(sub * 16 + j) * CC + 2 * slot];
            p1 += hv * w2s[(sub * 16 + j) * CC + 2 * slot + 1];
        }
        p0 += __shfl_xor(p0, 1); p0 += __shfl_xor(p0, 2); p0 += __shfl_xor(p0, 4);
        p1 += __shfl_xor(p1, 1); p1 += __shfl_xor(p1, 2); p1 += __shfl_xor(p1, 4);
        if (sub == 0) {
            uint_t packed = (uint_t)f2bf(p0) | ((uint_t)f2bf(p1) << 16);
            *(uint_t*)(h2b + (size_t)node * CC + 2 * slot) = packed;
        }
    }
}

// ---------------- agg2 + pool fused, sorted-batch segmented flush ----------------
__global__ __launch_bounds__(256) void agg2pool_kernel(const ushort_t* __restrict__ h2b,
                                                       const int* __restrict__ rowptr,
                                                       const uint_t* __restrict__ csr,
                                                       const float* __restrict__ dis,
                                                       const float* __restrict__ b2,
                                                       const int* __restrict__ batch,
                                                       float* __restrict__ pooled) {
    __shared__ float vals[16][16];
    __shared__ int gid[16];
    int t = threadIdx.x;
    int local = t >> 4, c = t & 15;
    int node = blockIdx.x * 16 + local;
    int e0 = rowptr[node], e1 = rowptr[node + 1];
    float acc = 0.0f;
    for (int e = e0; e < e1; e++) {
        uint_t ent = csr[e];
        acc += h2f((ushort_t)(ent >> 16)) * bf2f(h2b[(size_t)(ent & 0xFFFFu) * CC + c]);
    }
    vals[local][c] = acc * dis[node] + b2[c];
    if (c == 0) gid[local] = batch[node];
    __syncthreads();
    if (t < 16) {                      // walker for channel t
        float run = 0.0f;
        for (int i = 0; i < 16; i++) {
            run += vals[i][t];
            if (i == 15 || gid[i + 1] != gid[i]) {
                atomicAdd(&pooled[gid[i] * CC + t], run);
                run = 0.0f;
            }
        }
    }
}

// ---------------- mean + log_softmax (counts via binary search) ----------------
__global__ void lsm_kernel(const float* __restrict__ pooled,
                           const int* __restrict__ batch,
                           float* __restrict__ out) {
    int idx = blockIdx.x * blockDim.x + threadIdx.x;
    int g = idx >> 4, c = idx & 15;
    if (g >= GG) return;
    int lo = 0, hi = NN;
    while (lo < hi) { int mid = (lo + hi) >> 1; if (batch[mid] < g) lo = mid + 1; else hi = mid; }
    int lo2 = lo, hi2 = NN;
    while (lo2 < hi2) { int mid = (lo2 + hi2) >> 1; if (batch[mid] < g + 1) lo2 = mid + 1; else hi2 = mid; }
    float cnt = (float)(lo2 - lo);
    float v = pooled[g * CC + c] / fmaxf(cnt, 1.0f);
    float m = v;
    for (int off = 8; off >= 1; off >>= 1) m = fmaxf(m, __shfl_xor(m, off, 16));
    float s = expf(v - m);
    for (int off = 8; off >= 1; off >>= 1) s += __shfl_xor(s, off, 16);
    out[g * CC + c] = v - m - logf(s);
}

extern "C" void kernel_launch(void* const* d_in, const int* in_sizes, int n_in,
                              void* d_out, int out_size, void* d_ws, size_t ws_size,
                              hipStream_t stream) {
    const float* x  = (const float*)d_in[0];
    const float* W1 = (const float*)d_in[1];
    const float* b1 = (const float*)d_in[2];
    const float* W2 = (const float*)d_in[3];
    const float* b2 = (const float*)d_in[4];
    const int* edge_src = (const int*)d_in[5];
    const int* edge_dst = (const int*)d_in[6];
    const int* batch    = (const int*)d_in[7];
    float* out = (float*)d_out;

    char* ws = (char*)d_ws;
    size_t off = 0;
    auto alloc = [&](size_t bytes) {
        void* p = ws + off;
        off += (bytes + 255) & ~size_t(255);
        return p;
    };
    int*   cnt     = (int*)  alloc(NN * 4);
    float* dis     = (float*)alloc(NN * 4);
    int*   rowptr  = (int*)  alloc((NN + 1) * 4);
    int*   seq     = (int*)  alloc(EE * 4);
    int*   bsum    = (int*)  alloc(SBLK * 4);
    uint_t* csr    = (uint_t*)alloc((size_t)ETOT * 4);
    unsigned char* hb8 = (unsigned char*)alloc((size_t)NN * HH);
    ushort_t* h2b  = (ushort_t*)alloc((size_t)NN * CC * 2);
    float* pooled  = (float*)alloc(GG * CC * 4);

    const int B = 256;
    init_kernel<<<(NN + B - 1) / B, B, 0, stream>>>(cnt, pooled);
    count_kernel<<<(EE + B - 1) / B, B, 0, stream>>>(edge_dst, cnt, seq);
    gemm1_kernel<<<(NN + 63) / 64, B, 0, stream>>>(x, W1, hb8);
    scanA_kernel<<<SBLK, B, 0, stream>>>(cnt, rowptr, dis, bsum);
    scanBC_kernel<<<SBLK, B, 0, stream>>>(rowptr, bsum);
    fill_kernel<<<(ETOT + B - 1) / B, B, 0, stream>>>(edge_src, edge_dst, dis,
                                                      rowptr, seq, csr);
    agg1_kernel<<<NN / 16, B, 0, stream>>>(hb8, rowptr, csr, dis, b1, W2, h2b);
    agg2pool_kernel<<<NN / 16, B, 0, stream>>>(h2b, rowptr, csr, dis, b2, batch, pooled);
    lsm_kernel<<<(GG * CC + B - 1) / B, B, 0, stream>>>(pooled, batch, out);
}